// Round 14
// baseline (300.709 us; speedup 1.0000x reference)
//
#include <hip/hip_runtime.h>
#include <stdint.h>

constexpr int kN = 16384;
constexpr int kD = 256;
constexpr int TM = 256, TN = 256;   // block tile 256x256
constexpr int KB = kD / 2;          // fp4 row = 128 bytes

using floatx16 = __attribute__((ext_vector_type(16))) float;  // 32x32 MFMA C/D
using float2v  = __attribute__((ext_vector_type(2))) float;   // packed-math pair
using intx4    = __attribute__((ext_vector_type(4))) int;
using intx8    = __attribute__((ext_vector_type(8))) int;     // f8f6f4 operand

// fp32*16 -> fp4 e2m1 RNE. Codes 0..7 = {0,.5,1,1.5,2,3,4,6} ARE the bit
// patterns (monotone). Thresholds are the RNE midpoints. (R12-verified.)
__device__ __forceinline__ uint32_t q4(float x) {
    float y = fabsf(x * 16.f);
    uint32_t c = (y >= 0.25f) + (y >= 0.75f) + (y >= 1.25f) + (y >= 1.75f)
               + (y >= 2.5f)  + (y >= 3.5f)  + (y >= 5.0f);
    return c | (x < 0.f ? 8u : 0u);
}

// 8 elems -> one dword per matrix per thread (nibble i = elem 8*idx+i).
__global__ __launch_bounds__(256)
void cvt_fp4_kernel(const float* __restrict__ a, const float* __restrict__ b,
                    unsigned int* __restrict__ oa, unsigned int* __restrict__ ob) {
    int idx = blockIdx.x * 256 + threadIdx.x;
    float4 a0 = *(const float4*)(a + (size_t)idx * 8);
    float4 a1 = *(const float4*)(a + (size_t)idx * 8 + 4);
    float4 b0 = *(const float4*)(b + (size_t)idx * 8);
    float4 b1 = *(const float4*)(b + (size_t)idx * 8 + 4);
    uint32_t pa = q4(a0.x) | (q4(a0.y) << 4) | (q4(a0.z) << 8)  | (q4(a0.w) << 12)
                | (q4(a1.x) << 16) | (q4(a1.y) << 20) | (q4(a1.z) << 24) | (q4(a1.w) << 28);
    uint32_t pb = q4(b0.x) | (q4(b0.y) << 4) | (q4(b0.z) << 8)  | (q4(b0.w) << 12)
                | (q4(b1.x) << 16) | (q4(b1.y) << 20) | (q4(b1.z) << 24) | (q4(b1.w) << 28);
    oa[idx] = pa;
    ob[idx] = pb;
}

// R14 = R13 (barrier-free, LDS-free, A-resident MX-fp4 loop) +
//  (1) register double-buffered B prefetch: tile s+1 loads issue before tile
//      s's MFMA+epilogue (manual unroll-by-2) -> per-tile vmcnt stall gone;
//  (2) packed-pair Schraudolph epilogue: float2 ops -> v_pk_fma_f32/v_pk_add_f32.
// loss*N = sum_all exp(t) - sum_diag t,  t = sc/256*dot + bs
__global__ __launch_bounds__(512, 2)
void siglip_gemm_loss_kernel(const unsigned char* __restrict__ A,   // fp4 [N][KB]
                             const unsigned char* __restrict__ B,   // fp4 [N][KB]
                             const float* __restrict__ scale_p,
                             const float* __restrict__ bias_p,
                             float* __restrict__ out) {
    __shared__ float red[8];

    const int tid  = threadIdx.x;
    const int wave = tid >> 6;     // 0..7
    const int lane = tid & 63;

    const int g    = blockIdx.x;                  // 256 persistent blocks
    const int tRow = ((g & 7) << 3) + (g >> 5);   // fixed tile-row (A-stripe L2-hot)
    const int sCol = (g >> 3) & 3;                // tile s -> col sCol + 4s

    const int wr = wave >> 2, wc = wave & 3;   // 2x4 waves
    const int m0 = wr * 128, n0 = wc * 64;     // wave tile 128x64
    const int l31 = lane & 31;
    const int h   = lane >> 5;                 // K-half: byte offset 16h

    const float sc  = *scale_p * (1.0f / 256.0f);   // undo x16 x16 prescale
    const float bs  = *bias_p;
    const float sc3 = sc * (1.44269504f * 8388608.0f);
    const float bs3 = fmaf(bs, 1.44269504f * 8388608.0f, 1064986823.0f);
    const float2v sc2v = (float2v){sc3, sc3};
    const float2v bs2v = (float2v){bs3, bs3};

    // ---- A operand: loop-invariant, register-resident (R13-verified)
    intx4 af[4][4];
    #pragma unroll
    for (int i = 0; i < 4; ++i) {
        const unsigned char* pa = A + ((size_t)tRow * TM + m0 + i * 32 + l31) * KB + 16 * h;
        #pragma unroll
        for (int q = 0; q < 4; ++q)
            af[i][q] = *(const intx4*)(pa + q * 32);
    }

    floatx16 acc[4][2];
    #pragma unroll
    for (int i = 0; i < 4; ++i)
        #pragma unroll
        for (int j = 0; j < 2; ++j)
            acc[i][j] = (floatx16)(0.f);
    float2v sum2 = (float2v){0.f, 0.f};
    float dsum = 0.f;   // diagonal corrections (rare)

    // B fragment pointers (rows n0 + j*32 + l31); advance by 4 tile-cols/tile
    const unsigned char* pb0 = B + ((size_t)sCol * TN + n0 + l31) * KB + 16 * h;
    const unsigned char* pb1 = pb0 + 32 * KB;
    const size_t tStride = (size_t)4 * TN * KB;

    auto loadB = [&](intx4 (&bfr)[2][4]) {
        #pragma unroll
        for (int q = 0; q < 4; ++q) {
            bfr[0][q] = *(const intx4*)(pb0 + q * 32);
            bfr[1][q] = *(const intx4*)(pb1 + q * 32);
        }
        pb0 += tStride;
        pb1 += tStride;
    };

    auto computeTile = [&](const intx4 (&bfr)[2][4], int s) {
        #pragma unroll
        for (int q = 0; q < 4; ++q) {
            intx8 bop[2];
            #pragma unroll
            for (int j = 0; j < 2; ++j)
                bop[j] = (intx8){bfr[j][q].x, bfr[j][q].y, bfr[j][q].z, bfr[j][q].w,
                                 0, 0, 0, 0};
            #pragma unroll
            for (int i = 0; i < 4; ++i) {
                const intx8 aop = (intx8){af[i][q].x, af[i][q].y, af[i][q].z, af[i][q].w,
                                          0, 0, 0, 0};
                #pragma unroll
                for (int j = 0; j < 2; ++j)
                    acc[i][j] = __builtin_amdgcn_mfma_scale_f32_32x32x64_f8f6f4(
                        aop, bop[j], acc[i][j],
                        4 /*A=fp4*/, 4 /*B=fp4*/, 0, 127, 0, 127);
            }
        }
        // epilogue: packed-pair Schraudolph, fold into running sums, reset acc
        const int tCol = sCol + 4 * s;
        #pragma unroll
        for (int i = 0; i < 4; ++i)
            #pragma unroll
            for (int j = 0; j < 2; ++j) {
                #pragma unroll
                for (int v = 0; v < 16; v += 2) {
                    float2v t = (float2v){acc[i][j][v], acc[i][j][v + 1]};
                    t = t * sc2v + bs2v;                      // v_pk_fma_f32
                    float2v r;
                    r.x = __int_as_float((int)t.x);           // scalar cvt
                    r.y = __int_as_float((int)t.y);
                    sum2 += r;                                // v_pk_add_f32
                }
                const int gRow0 = tRow * TM + m0 + i * 32;
                const int gCol0 = tCol * TN + n0 + j * 32;
                if (gRow0 == gCol0) {   // wave-uniform, rare: diag correction
                    #pragma unroll
                    for (int v = 0; v < 16; ++v) {
                        const int rrow = (v & 3) + 8 * (v >> 2) + 4 * h;
                        if (rrow == l31)
                            dsum += fmaf(acc[i][j][v], sc, bs);
                    }
                }
                acc[i][j] = (floatx16)(0.f);
            }
    };

    // software pipeline, unroll-by-2: prefetch next tile's B before computing
    intx4 b0[2][4], b1[2][4];
    loadB(b0);                       // tile 0
    for (int s2 = 0; s2 < 16; s2 += 2) {
        loadB(b1);                   // tile s2+1 (in flight during compute)
        computeTile(b0, s2);
        if (s2 + 2 < 16) loadB(b0);  // tile s2+2
        computeTile(b1, s2 + 1);
    }

    float sum = sum2.x + sum2.y - dsum;

    // block reduce -> ONE atomicAdd per block (256 total; R13-verified benign)
    #pragma unroll
    for (int off = 32; off > 0; off >>= 1)
        sum += __shfl_down(sum, off);
    if (lane == 0) red[wave] = sum;
    __syncthreads();
    if (tid == 0) {
        float s2 = 0.f;
        #pragma unroll
        for (int w = 0; w < 8; ++w) s2 += red[w];
        atomicAdd(out, s2 * (1.0f / (float)kN));
    }
}

extern "C" void kernel_launch(void* const* d_in, const int* in_sizes, int n_in,
                              void* d_out, int out_size, void* d_ws, size_t ws_size,
                              hipStream_t stream) {
    const float* img     = (const float*)d_in[0];
    const float* txt     = (const float*)d_in[1];
    const float* scale_p = (const float*)d_in[2];
    const float* bias_p  = (const float*)d_in[3];
    float* out = (float*)d_out;

    unsigned char* Af4 = (unsigned char*)d_ws;            // N*KB = 2 MiB
    unsigned char* Bf4 = Af4 + (size_t)kN * KB;           // 2 MiB

    hipMemsetAsync(out, 0, sizeof(float), stream);        // capture-safe
    cvt_fp4_kernel<<<dim3(kN * kD / 8 / 256), dim3(256), 0, stream>>>(
        img, txt, (unsigned int*)Af4, (unsigned int*)Bf4);
    siglip_gemm_loss_kernel<<<dim3(256), dim3(512), 0, stream>>>(
        Af4, Bf4, scale_p, bias_p, out);
}

// Round 15
// 121.398 us; speedup vs baseline: 2.4770x; 2.4770x over previous
//
#include <hip/hip_runtime.h>
#include <stdint.h>

constexpr int kN = 16384;
constexpr int kD = 256;
constexpr int TM = 256, TN = 256;   // block tile 256x256
constexpr int KB = kD / 2;          // fp4 row = 128 bytes

using floatx16 = __attribute__((ext_vector_type(16))) float;  // 32x32 MFMA C/D
using float2v  = __attribute__((ext_vector_type(2))) float;   // packed-math pair
using intx4    = __attribute__((ext_vector_type(4))) int;
using intx8    = __attribute__((ext_vector_type(8))) int;     // f8f6f4 operand

// fp32*16 -> fp4 e2m1 RNE. Codes 0..7 = {0,.5,1,1.5,2,3,4,6} ARE the bit
// patterns (monotone). Thresholds are the RNE midpoints. (R12-verified.)
__device__ __forceinline__ uint32_t q4(float x) {
    float y = fabsf(x * 16.f);
    uint32_t c = (y >= 0.25f) + (y >= 0.75f) + (y >= 1.25f) + (y >= 1.75f)
               + (y >= 2.5f)  + (y >= 3.5f)  + (y >= 5.0f);
    return c | (x < 0.f ? 8u : 0u);
}

// 8 elems -> one dword per matrix per thread (nibble i = elem 8*idx+i).
__global__ __launch_bounds__(256)
void cvt_fp4_kernel(const float* __restrict__ a, const float* __restrict__ b,
                    unsigned int* __restrict__ oa, unsigned int* __restrict__ ob) {
    int idx = blockIdx.x * 256 + threadIdx.x;
    float4 a0 = *(const float4*)(a + (size_t)idx * 8);
    float4 a1 = *(const float4*)(a + (size_t)idx * 8 + 4);
    float4 b0 = *(const float4*)(b + (size_t)idx * 8);
    float4 b1 = *(const float4*)(b + (size_t)idx * 8 + 4);
    uint32_t pa = q4(a0.x) | (q4(a0.y) << 4) | (q4(a0.z) << 8)  | (q4(a0.w) << 12)
                | (q4(a1.x) << 16) | (q4(a1.y) << 20) | (q4(a1.z) << 24) | (q4(a1.w) << 28);
    uint32_t pb = q4(b0.x) | (q4(b0.y) << 4) | (q4(b0.z) << 8)  | (q4(b0.w) << 12)
                | (q4(b1.x) << 16) | (q4(b1.y) << 20) | (q4(b1.z) << 24) | (q4(b1.w) << 28);
    oa[idx] = pa;
    ob[idx] = pb;
}

// R15 = R13 exactly (barrier-free, LDS-free, A-register-resident MX-fp4 loop;
// single B buffer — R14's second buffer broke the 256-reg budget and the
// compiler rematerialized A from HBM: 406 MB FETCH, 5x regression) + the
// register-neutral packed-pair Schraudolph epilogue (transient float2 only).
// loss*N = sum_all exp(t) - sum_diag t,  t = sc/256*dot + bs
__global__ __launch_bounds__(512, 2)
void siglip_gemm_loss_kernel(const unsigned char* __restrict__ A,   // fp4 [N][KB]
                             const unsigned char* __restrict__ B,   // fp4 [N][KB]
                             const float* __restrict__ scale_p,
                             const float* __restrict__ bias_p,
                             float* __restrict__ out) {
    __shared__ float red[8];

    const int tid  = threadIdx.x;
    const int wave = tid >> 6;     // 0..7
    const int lane = tid & 63;

    const int g    = blockIdx.x;                  // 256 persistent blocks
    const int tRow = ((g & 7) << 3) + (g >> 5);   // fixed tile-row (A-stripe L2-hot)
    const int sCol = (g >> 3) & 3;                // tile s -> col sCol + 4s

    const int wr = wave >> 2, wc = wave & 3;   // 2x4 waves
    const int m0 = wr * 128, n0 = wc * 64;     // wave tile 128x64
    const int l31 = lane & 31;
    const int h   = lane >> 5;                 // K-half: byte offset 16h

    const float sc  = *scale_p * (1.0f / 256.0f);   // undo x16 x16 prescale
    const float bs  = *bias_p;
    const float sc3 = sc * (1.44269504f * 8388608.0f);
    const float bs3 = fmaf(bs, 1.44269504f * 8388608.0f, 1064986823.0f);
    const float2v sc2v = (float2v){sc3, sc3};
    const float2v bs2v = (float2v){bs3, bs3};

    // ---- A operand: loop-invariant, register-resident (R13-verified)
    intx4 af[4][4];
    #pragma unroll
    for (int i = 0; i < 4; ++i) {
        const unsigned char* pa = A + ((size_t)tRow * TM + m0 + i * 32 + l31) * KB + 16 * h;
        #pragma unroll
        for (int q = 0; q < 4; ++q)
            af[i][q] = *(const intx4*)(pa + q * 32);
    }

    floatx16 acc[4][2];
    #pragma unroll
    for (int i = 0; i < 4; ++i)
        #pragma unroll
        for (int j = 0; j < 2; ++j)
            acc[i][j] = (floatx16)(0.f);
    float2v sum2 = (float2v){0.f, 0.f};
    float dsum = 0.f;   // diagonal corrections (rare)

    // B fragment base pointers (rows n0 + j*32 + l31 of col-tile sCol)
    const unsigned char* pb0 = B + ((size_t)sCol * TN + n0 + l31) * KB + 16 * h;
    const unsigned char* pb1 = pb0 + 32 * KB;
    const size_t tStride = (size_t)4 * TN * KB;   // tile col advances by 4

    for (int s = 0; s < 16; ++s) {
        // 8 B-fragment loads for this tile (compiler pipelines via vmcnt)
        intx4 bfr[2][4];
        #pragma unroll
        for (int q = 0; q < 4; ++q) {
            bfr[0][q] = *(const intx4*)(pb0 + q * 32);
            bfr[1][q] = *(const intx4*)(pb1 + q * 32);
        }
        pb0 += tStride;
        pb1 += tStride;

        #pragma unroll
        for (int q = 0; q < 4; ++q) {
            intx8 bop[2];
            #pragma unroll
            for (int j = 0; j < 2; ++j)
                bop[j] = (intx8){bfr[j][q].x, bfr[j][q].y, bfr[j][q].z, bfr[j][q].w,
                                 0, 0, 0, 0};
            #pragma unroll
            for (int i = 0; i < 4; ++i) {
                const intx8 aop = (intx8){af[i][q].x, af[i][q].y, af[i][q].z, af[i][q].w,
                                          0, 0, 0, 0};
                #pragma unroll
                for (int j = 0; j < 2; ++j)
                    acc[i][j] = __builtin_amdgcn_mfma_scale_f32_32x32x64_f8f6f4(
                        aop, bop[j], acc[i][j],
                        4 /*cbsz: A=fp4*/, 4 /*blgp: B=fp4*/,
                        0, 127, 0, 127 /*neutral e8m0 scales*/);
            }
        }

        {   // epilogue: packed-pair Schraudolph, fold into running sums, reset acc
            const int tCol = sCol + 4 * s;
            #pragma unroll
            for (int i = 0; i < 4; ++i)
                #pragma unroll
                for (int j = 0; j < 2; ++j) {
                    #pragma unroll
                    for (int v = 0; v < 16; v += 2) {
                        float2v t = (float2v){acc[i][j][v], acc[i][j][v + 1]};
                        t = t * sc2v + bs2v;                  // v_pk_fma_f32
                        float2v r;
                        r.x = __int_as_float((int)t.x);       // scalar cvt
                        r.y = __int_as_float((int)t.y);
                        sum2 += r;                            // v_pk_add_f32
                    }
                    // diagonal correction: term_diag = term_off - t
                    const int gRow0 = tRow * TM + m0 + i * 32;
                    const int gCol0 = tCol * TN + n0 + j * 32;
                    if (gRow0 == gCol0) {   // wave-uniform, rare
                        #pragma unroll
                        for (int v = 0; v < 16; ++v) {
                            const int rrow = (v & 3) + 8 * (v >> 2) + 4 * h;
                            if (rrow == l31)
                                dsum += fmaf(acc[i][j][v], sc, bs);
                        }
                    }
                    acc[i][j] = (floatx16)(0.f);
                }
        }
    }

    float sum = sum2.x + sum2.y - dsum;

    // block reduce -> ONE atomicAdd per block (256 total; R13-verified benign)
    #pragma unroll
    for (int off = 32; off > 0; off >>= 1)
        sum += __shfl_down(sum, off);
    if (lane == 0) red[wave] = sum;
    __syncthreads();
    if (tid == 0) {
        float s2 = 0.f;
        #pragma unroll
        for (int w = 0; w < 8; ++w) s2 += red[w];
        atomicAdd(out, s2 * (1.0f / (float)kN));
    }
}

extern "C" void kernel_launch(void* const* d_in, const int* in_sizes, int n_in,
                              void* d_out, int out_size, void* d_ws, size_t ws_size,
                              hipStream_t stream) {
    const float* img     = (const float*)d_in[0];
    const float* txt     = (const float*)d_in[1];
    const float* scale_p = (const float*)d_in[2];
    const float* bias_p  = (const float*)d_in[3];
    float* out = (float*)d_out;

    unsigned char* Af4 = (unsigned char*)d_ws;            // N*KB = 2 MiB
    unsigned char* Bf4 = Af4 + (size_t)kN * KB;           // 2 MiB

    hipMemsetAsync(out, 0, sizeof(float), stream);        // capture-safe
    cvt_fp4_kernel<<<dim3(kN * kD / 8 / 256), dim3(256), 0, stream>>>(
        img, txt, (unsigned int*)Af4, (unsigned int*)Bf4);
    siglip_gemm_loss_kernel<<<dim3(256), dim3(512), 0, stream>>>(
        Af4, Bf4, scale_p, bias_p, out);
}